// Round 6
// baseline (4280.427 us; speedup 1.0000x reference)
//
#include <hip/hip_runtime.h>

using u16 = unsigned short;
using u32 = unsigned int;

#define DI __device__ __forceinline__

typedef __bf16 bf16x8 __attribute__((ext_vector_type(8)));
typedef float  f32x4  __attribute__((ext_vector_type(4)));

DI float b2f(u16 u){ u32 x = ((u32)u) << 16; float f; __builtin_memcpy(&f, &x, 4); return f; }
// native RNE f32->bf16 (compiler emits v_cvt_pk_bf16_f32)
DI u16 f2b(float f){ __bf16 h = (__bf16)f; u16 r; __builtin_memcpy(&r, &h, 2); return r; }
// tanh-form GELU: |err vs erf-GELU| <= ~5e-4 absolute
DI float gelu_fast(float v){
    float u = v * (0.7978845608f + 0.0356774081f * v * v);
    float e = __expf(2.0f * u);
    float t = 1.0f - 2.0f / (e + 1.0f);
    return 0.5f * v * (1.0f + t);
}

#define GLOAD16(g, l) __builtin_amdgcn_global_load_lds( \
    (const __attribute__((address_space(1))) void*)(g), \
    (__attribute__((address_space(3))) void*)(l), 16, 0, 0)

// ---------------------------------------------------------------------------
// Generic bf16 GEMM:  C[M][N] = A[M][K] @ Bt[N][K]^T + bias
// Triple-buffered pipeline, prefetch distance 2, counted vmcnt(4) (T4):
// tile t+1 loads stay in flight across the barrier; only tile t is awaited.
// Read-side XOR swizzle + inverse-swizzled global source (conflicts = 0, r5).
// EPI: 0 = bias, store bf16; 1 = bias+GELU, store bf16; 2 = bias, store f32
// ---------------------------------------------------------------------------
template<int EPI>
__global__ __launch_bounds__(256)
void gemm_bt(const u16* __restrict__ A, const u16* __restrict__ Bt,
             const float* __restrict__ bias, void* __restrict__ Cout,
             int M, int N, int K)
{
    __shared__ u16 lA[3][128 * 32];
    __shared__ u16 lB[3][128 * 32];
    const int tid  = threadIdx.x;
    const int lane = tid & 63;
    const int w    = tid >> 6;
    const int wm   = w >> 1, wn = w & 1;

    const int nx = gridDim.x;
    const int nb = nx * gridDim.y;
    int bid = blockIdx.y * nx + blockIdx.x;
    if ((nb & 7) == 0) bid = ((bid & 7) * (nb >> 3)) + (bid >> 3);
    const int m0 = (bid / nx) * 128;
    const int n0 = (bid % nx) * 128;

    f32x4 acc[4][4] = {};

    const int srow = tid >> 2;                                  // 0..63
    const int scol = (((tid & 3) ^ ((tid >> 3) & 3)) * 8);      // inverse-swizzled source chunk
    int ar0 = m0 + srow;      if (ar0 > M - 1) ar0 = M - 1;
    int ar1 = m0 + 64 + srow; if (ar1 > M - 1) ar1 = M - 1;
    const u16* gA0 = A  + (size_t)ar0 * K + scol;
    const u16* gA1 = A  + (size_t)ar1 * K + scol;
    const u16* gB0 = Bt + (size_t)(n0 + srow) * K + scol;
    const u16* gB1 = Bt + (size_t)(n0 + 64 + srow) * K + scol;

    const int la = lane & 15, lg = lane >> 4;
    const int cp = (lg ^ ((la >> 1) & 3)) * 8;                  // swizzled read chunk

    const int nt = K >> 5;      // K is a multiple of 32 and >= 768 here (nt >= 24)

    // prologue: stage tiles 0 and 1 (8 loads in flight)
    GLOAD16(gA0,      &lA[0][tid * 8]);
    GLOAD16(gA1,      &lA[0][tid * 8 + 2048]);
    GLOAD16(gB0,      &lB[0][tid * 8]);
    GLOAD16(gB1,      &lB[0][tid * 8 + 2048]);
    GLOAD16(gA0 + 32, &lA[1][tid * 8]);
    GLOAD16(gA1 + 32, &lA[1][tid * 8 + 2048]);
    GLOAD16(gB0 + 32, &lB[1][tid * 8]);
    GLOAD16(gB1 + 32, &lB[1][tid * 8 + 2048]);

    int cur = 0, pre = 2;       // buffer indices: read cur, stage into pre
    for (int t = 0; t < nt; ++t) {
        // wait for tile t only; tile t+1's 4 loads remain in flight
        if (t + 1 < nt) asm volatile("s_waitcnt vmcnt(4)" ::: "memory");
        else            asm volatile("s_waitcnt vmcnt(0)" ::: "memory");
        __builtin_amdgcn_s_barrier();
        asm volatile("" ::: "memory");

        if (t + 2 < nt) {       // stage tile t+2 (overwrites buffer read in iter t-1;
            const int k0 = (t + 2) << 5;  // safe: those reads were consumed pre-barrier)
            GLOAD16(gA0 + k0, &lA[pre][tid * 8]);
            GLOAD16(gA1 + k0, &lA[pre][tid * 8 + 2048]);
            GLOAD16(gB0 + k0, &lB[pre][tid * 8]);
            GLOAD16(gB1 + k0, &lB[pre][tid * 8 + 2048]);
        }

        bf16x8 af[4], bfr[4];
        #pragma unroll
        for (int i = 0; i < 4; i++)
            af[i] = *(const bf16x8*)&lA[cur][(wm * 64 + i * 16 + la) * 32 + cp];
        #pragma unroll
        for (int j = 0; j < 4; j++)
            bfr[j] = *(const bf16x8*)&lB[cur][(wn * 64 + j * 16 + la) * 32 + cp];
        #pragma unroll
        for (int i = 0; i < 4; i++)
            #pragma unroll
            for (int j = 0; j < 4; j++)
                acc[i][j] = __builtin_amdgcn_mfma_f32_16x16x32_bf16(af[i], bfr[j], acc[i][j], 0, 0, 0);

        cur = (cur == 2) ? 0 : cur + 1;
        pre = (pre == 2) ? 0 : pre + 1;
    }

    #pragma unroll
    for (int i = 0; i < 4; i++) {
        const int rowb = m0 + wm * 64 + i * 16 + lg * 4;
        #pragma unroll
        for (int j = 0; j < 4; j++) {
            const int col = n0 + wn * 64 + j * 16 + la;
            const float bv = bias[col];
            #pragma unroll
            for (int r = 0; r < 4; r++) {
                const int rr = rowb + r;
                if (rr < M) {
                    float v = acc[i][j][r] + bv;
                    if constexpr (EPI == 1) v = gelu_fast(v);
                    if constexpr (EPI == 2) ((float*)Cout)[(size_t)rr * N + col] = v;
                    else                    ((u16*)Cout)[(size_t)rr * N + col] = f2b(v);
                }
            }
        }
    }
}

// ---------------------------------------------------------------------------
// fp32 [z][K][N] -> bf16 [z][N][K] transpose-convert
// ---------------------------------------------------------------------------
__global__ __launch_bounds__(256)
void transp_conv(const float* __restrict__ in, u16* __restrict__ out, int K, int N)
{
    __shared__ float tile[32][33];
    const int l = blockIdx.z;
    const float* inp = in + (size_t)l * K * N;
    u16* op = out + (size_t)l * K * N;
    const int kb = blockIdx.y * 32, nb = blockIdx.x * 32;
    const int tx = threadIdx.x, ty = threadIdx.y;
    #pragma unroll
    for (int i = 0; i < 32; i += 8)
        tile[ty + i][tx] = inp[(size_t)(kb + ty + i) * N + nb + tx];
    __syncthreads();
    #pragma unroll
    for (int i = 0; i < 32; i += 8)
        op[(size_t)(nb + ty + i) * K + kb + tx] = f2b(tile[tx][ty + i]);
}

// ---------------------------------------------------------------------------
// Embedding
// ---------------------------------------------------------------------------
__global__ __launch_bounds__(192)
void embed_k(const int* __restrict__ ids, const float* __restrict__ te,
             const float* __restrict__ pe, const float* __restrict__ ue,
             u16* __restrict__ X)
{
    const int tok = blockIdx.x;
    const int l = tok & 63;
    const int t = (tok >> 6) & 63;
    const int id = ids[tok];
    const int c = threadIdx.x * 4;
    float4 a = *(const float4*)&te[(size_t)id * 768 + c];
    float4 p = *(const float4*)&pe[(size_t)l * 768 + c];
    float4 u = *(const float4*)&ue[(size_t)t * 768 + c];
    ushort4 o;
    o.x = f2b(a.x + p.x + u.x); o.y = f2b(a.y + p.y + u.y);
    o.z = f2b(a.z + p.z + u.z); o.w = f2b(a.w + p.w + u.w);
    *(ushort4*)&X[(size_t)tok * 768 + c] = o;
}

// m_t gather: mt[bt] = M[b, sid[bt]]
__global__ __launch_bounds__(256)
void gather_mt(const float* __restrict__ M, const int* __restrict__ sid,
               float* __restrict__ mt)
{
    const int bt = blockIdx.x, b = bt >> 6, tid = threadIdx.x;
    const float* src = M + ((size_t)b * 4 + sid[bt]) * 768;
    float* dst = mt + (size_t)bt * 768;
    dst[tid] = src[tid]; dst[tid + 256] = src[tid + 256]; dst[tid + 512] = src[tid + 512];
}

// Ain = (X + mt[bt]) * mask  (bf16 out)
__global__ __launch_bounds__(192)
void prep_ain(const u16* __restrict__ X, const float* __restrict__ mt,
              const int* __restrict__ mask, u16* __restrict__ Ain)
{
    const int tok = blockIdx.x, bt = tok >> 6;
    const float mk = (float)mask[tok];
    const int c = threadIdx.x * 4;
    ushort4 xv = *(const ushort4*)&X[(size_t)tok * 768 + c];
    float4 mv = *(const float4*)&mt[(size_t)bt * 768 + c];
    ushort4 o;
    o.x = f2b((b2f(xv.x) + mv.x) * mk); o.y = f2b((b2f(xv.y) + mv.y) * mk);
    o.z = f2b((b2f(xv.z) + mv.z) * mk); o.w = f2b((b2f(xv.w) + mv.w) * mk);
    *(ushort4*)&Ain[(size_t)tok * 768 + c] = o;
}

// ---------------------------------------------------------------------------
// Self-attention per (bt_local, head). XOR-swizzled LDS (write+read involution).
// ---------------------------------------------------------------------------
DI int swz(int row, int col) { return row * 64 + (((col >> 3) ^ (row & 7)) << 3) + (col & 7); }

__global__ __launch_bounds__(256)
void attn_self(const u16* __restrict__ QKV, u16* __restrict__ O)
{
    __shared__ u16 lQ[64 * 64], lK[64 * 64], lVt[64 * 64], lP[64 * 64];
    __shared__ float lS[64 * 68];
    const int bt = blockIdx.x / 12, h = blockIdx.x % 12;
    const int tid = threadIdx.x, lane = tid & 63, w = tid >> 6;
    const size_t base = (size_t)bt * 64 * 2304;

    #pragma unroll
    for (int it = 0; it < 2; ++it) {
        const int slot = it * 256 + tid;
        const int l = slot >> 3, dc = (slot & 7) * 8;
        const u16* qp = QKV + base + (size_t)l * 2304 + h * 64 + dc;
        *(uint4*)&lQ[swz(l, dc)] = *(const uint4*)qp;
        *(uint4*)&lK[swz(l, dc)] = *(const uint4*)(qp + 768);
        uint4 vv = *(const uint4*)(qp + 1536);
        u16 tmp[8]; *(uint4*)tmp = vv;
        #pragma unroll
        for (int j = 0; j < 8; j++) lVt[swz(dc + j, l)] = tmp[j];
    }
    __syncthreads();

    const int la = lane & 15, lg = lane >> 4;
    {   // s = Q K^T / 8 ; wave w owns q-rows [w*16, w*16+16)
        f32x4 sa[4] = {};
        #pragma unroll
        for (int kh = 0; kh < 64; kh += 32) {
            bf16x8 aq = *(const bf16x8*)&lQ[swz(w * 16 + la, kh + lg * 8)];
            #pragma unroll
            for (int fn = 0; fn < 4; ++fn) {
                bf16x8 bk = *(const bf16x8*)&lK[swz(fn * 16 + la, kh + lg * 8)];
                sa[fn] = __builtin_amdgcn_mfma_f32_16x16x32_bf16(aq, bk, sa[fn], 0, 0, 0);
            }
        }
        #pragma unroll
        for (int fn = 0; fn < 4; ++fn)
            #pragma unroll
            for (int r = 0; r < 4; ++r)
                lS[(w * 16 + lg * 4 + r) * 68 + fn * 16 + la] = sa[fn][r] * 0.125f;
    }
    __syncthreads();

    {   // softmax over k (row = q), 4 lanes per row
        const int row = tid >> 2, q4 = tid & 3;
        float e[16]; float mx = -1e30f;
        #pragma unroll
        for (int j = 0; j < 16; j++) { e[j] = lS[row * 68 + q4 * 16 + j]; mx = fmaxf(mx, e[j]); }
        mx = fmaxf(mx, __shfl_xor(mx, 1)); mx = fmaxf(mx, __shfl_xor(mx, 2));
        float sm = 0.f;
        #pragma unroll
        for (int j = 0; j < 16; j++) { e[j] = __expf(e[j] - mx); sm += e[j]; }
        sm += __shfl_xor(sm, 1); sm += __shfl_xor(sm, 2);
        const float inv = 1.0f / sm;
        #pragma unroll
        for (int j = 0; j < 16; j++) lP[swz(row, q4 * 16 + j)] = f2b(e[j] * inv);
    }
    __syncthreads();

    {   // O = P V
        f32x4 oa[4] = {};
        #pragma unroll
        for (int kh = 0; kh < 64; kh += 32) {
            bf16x8 ap = *(const bf16x8*)&lP[swz(w * 16 + la, kh + lg * 8)];
            #pragma unroll
            for (int fn = 0; fn < 4; ++fn) {
                bf16x8 bv = *(const bf16x8*)&lVt[swz(fn * 16 + la, kh + lg * 8)];
                oa[fn] = __builtin_amdgcn_mfma_f32_16x16x32_bf16(ap, bv, oa[fn], 0, 0, 0);
            }
        }
        const size_t ob = (size_t)bt * 64 * 768 + h * 64;
        #pragma unroll
        for (int fn = 0; fn < 4; ++fn)
            #pragma unroll
            for (int r = 0; r < 4; ++r)
                O[ob + (size_t)(w * 16 + lg * 4 + r) * 768 + fn * 16 + la] = f2b(oa[fn][r]);
    }
}

DI float wave_red(float v) {
    #pragma unroll
    for (int o = 32; o > 0; o >>= 1) v += __shfl_xor(v, o);
    return v;
}

// LN over H=768 of (a + b), bf16 in, bf16 out; grid = rows
__global__ __launch_bounds__(256)
void ln_res(const u16* __restrict__ a, const u16* __restrict__ b,
            const float* __restrict__ g, const float* __restrict__ be,
            u16* __restrict__ out)
{
    __shared__ float red[8];
    const int tid = threadIdx.x;
    const size_t off = (size_t)blockIdx.x * 768;
    float x0 = b2f(a[off + tid])       + b2f(b[off + tid]);
    float x1 = b2f(a[off + tid + 256]) + b2f(b[off + tid + 256]);
    float x2 = b2f(a[off + tid + 512]) + b2f(b[off + tid + 512]);
    float s = wave_red(x0 + x1 + x2);
    float ss = wave_red(x0 * x0 + x1 * x1 + x2 * x2);
    if ((tid & 63) == 0) { red[tid >> 6] = s; red[4 + (tid >> 6)] = ss; }
    __syncthreads();
    s = red[0] + red[1] + red[2] + red[3];
    ss = red[4] + red[5] + red[6] + red[7];
    const float mean = s * (1.f / 768.f);
    const float var = fmaxf(ss * (1.f / 768.f) - mean * mean, 0.f);
    const float inv = rsqrtf(var + 1e-5f);
    out[off + tid]       = f2b((x0 - mean) * inv * g[tid]       + be[tid]);
    out[off + tid + 256] = f2b((x1 - mean) * inv * g[tid + 256] + be[tid + 256]);
    out[off + tid + 512] = f2b((x2 - mean) * inv * g[tid + 512] + be[tid + 512]);
}

// LN over H=768 of (a + b), f32 in, f32 out
__global__ __launch_bounds__(256)
void ln_upd(const float* __restrict__ a, const float* __restrict__ b,
            const float* __restrict__ g, const float* __restrict__ be,
            float* __restrict__ out)
{
    __shared__ float red[8];
    const int tid = threadIdx.x;
    const size_t off = (size_t)blockIdx.x * 768;
    float x0 = a[off + tid]       + b[off + tid];
    float x1 = a[off + tid + 256] + b[off + tid + 256];
    float x2 = a[off + tid + 512] + b[off + tid + 512];
    float s = wave_red(x0 + x1 + x2);
    float ss = wave_red(x0 * x0 + x1 * x1 + x2 * x2);
    if ((tid & 63) == 0) { red[tid >> 6] = s; red[4 + (tid >> 6)] = ss; }
    __syncthreads();
    s = red[0] + red[1] + red[2] + red[3];
    ss = red[4] + red[5] + red[6] + red[7];
    const float mean = s * (1.f / 768.f);
    const float var = fmaxf(ss * (1.f / 768.f) - mean * mean, 0.f);
    const float inv = rsqrtf(var + 1e-5f);
    out[off + tid]       = (x0 - mean) * inv * g[tid]       + be[tid];
    out[off + tid + 256] = (x1 - mean) * inv * g[tid + 256] + be[tid + 256];
    out[off + tid + 512] = (x2 - mean) * inv * g[tid + 512] + be[tid + 512];
}

// tc = mean over L of X ; grid 512 (bt)
__global__ __launch_bounds__(256)
void tc_mean(const u16* __restrict__ X, u16* __restrict__ tcb)
{
    const int bt = blockIdx.x, tid = threadIdx.x;
    float s0 = 0, s1 = 0, s2 = 0;
    for (int l = 0; l < 64; ++l) {
        const u16* r = X + ((size_t)bt * 64 + l) * 768;
        s0 += b2f(r[tid]); s1 += b2f(r[tid + 256]); s2 += b2f(r[tid + 512]);
    }
    tcb[(size_t)bt * 768 + tid]       = f2b(s0 * (1.f / 64.f));
    tcb[(size_t)bt * 768 + tid + 256] = f2b(s1 * (1.f / 64.f));
    tcb[(size_t)bt * 768 + tid + 512] = f2b(s2 * (1.f / 64.f));
}

// f32 -> bf16 convert
__global__ __launch_bounds__(256)
void conv_bf16(const float* __restrict__ in, u16* __restrict__ out, int n)
{
    const int i = blockIdx.x * 256 + threadIdx.x;
    if (i < n) out[i] = f2b(in[i]);
}

// zero f32 buffer
__global__ __launch_bounds__(256)
void zero_f32(float* __restrict__ buf, int n)
{
    const int i = blockIdx.x * 256 + threadIdx.x;
    if (i < n) buf[i] = 0.f;
}

// cross-attention per (b,t): 4 heads over S=4 speakers; grid 512
__global__ __launch_bounds__(256)
void cross_attn(const u16* __restrict__ qc, const u16* __restrict__ kvc,
                u16* __restrict__ cca)
{
    __shared__ float q[768], kk[4][768], vv[4][768], sraw[16], aw[16];
    const int bt = blockIdx.x, b = bt >> 6, tid = threadIdx.x;
    #pragma unroll
    for (int i = 0; i < 3; i++) q[tid + i * 256] = b2f(qc[(size_t)bt * 768 + tid + i * 256]);
    #pragma unroll
    for (int i = 0; i < 12; i++) {
        const int idx = i * 256 + tid;
        const int s = idx / 768, d = idx % 768;
        kk[s][d] = b2f(kvc[(size_t)(b * 4 + s) * 1536 + d]);
        vv[s][d] = b2f(kvc[(size_t)(b * 4 + s) * 1536 + 768 + d]);
    }
    __syncthreads();
    if (tid < 16) {
        const int hh = tid >> 2, s = tid & 3;
        float acc = 0.f;
        for (int d = 0; d < 192; ++d) acc += q[hh * 192 + d] * kk[s][hh * 192 + d];
        sraw[tid] = acc * 0.07216878364870323f; // 1/sqrt(192)
    }
    __syncthreads();
    if (tid < 4) {
        float m = -1e30f;
        for (int s = 0; s < 4; s++) m = fmaxf(m, sraw[tid * 4 + s]);
        float ee[4], sm = 0.f;
        for (int s = 0; s < 4; s++) { ee[s] = __expf(sraw[tid * 4 + s] - m); sm += ee[s]; }
        for (int s = 0; s < 4; s++) aw[tid * 4 + s] = ee[s] / sm;
    }
    __syncthreads();
    #pragma unroll
    for (int i = 0; i < 3; i++) {
        const int j = tid + i * 256;
        const int hh = j / 192;
        float v = aw[hh * 4 + 0] * vv[0][j] + aw[hh * 4 + 1] * vv[1][j]
                + aw[hh * 4 + 2] * vv[2][j] + aw[hh * 4 + 3] * vv[3][j];
        cca[(size_t)bt * 768 + j] = f2b(v);
    }
}

// fused = [tc | m_t | cc]  bf16, grid 512
__global__ __launch_bounds__(256)
void concat_fused(const u16* __restrict__ tcb, const float* __restrict__ mt,
                  const u16* __restrict__ ccp, u16* __restrict__ Fu)
{
    const int bt = blockIdx.x, tid = threadIdx.x;
    u16* o = Fu + (size_t)bt * 2304;
    #pragma unroll
    for (int i = 0; i < 3; i++) {
        const int j = tid + i * 256;
        o[j]        = tcb[(size_t)bt * 768 + j];
        o[768 + j]  = f2b(mt[(size_t)bt * 768 + j]);
        o[1536 + j] = ccp[(size_t)bt * 768 + j];
    }
}

// per-(b,s) mean of upd over that speaker's turns; grid 32
__global__ __launch_bounds__(256)
void scatter_mem(const float* __restrict__ upd, const int* __restrict__ sid,
                 const float* __restrict__ counts, float* __restrict__ M)
{
    const int bs = blockIdx.x, b = bs >> 2, s = bs & 3, tid = threadIdx.x;
    const float c = counts[bs];
    #pragma unroll
    for (int i = 0; i < 3; i++) {
        const int j = tid + i * 256;
        float acc = 0.f;
        for (int t = 0; t < 64; ++t)
            if (sid[b * 64 + t] == s) acc += upd[((size_t)b * 64 + t) * 768 + j];
        if (c > 0.f) M[(size_t)bs * 768 + j] = acc / fmaxf(c, 1.f);
    }
}

__global__ void calc_counts(const int* __restrict__ sid, float* __restrict__ counts)
{
    const int tid = threadIdx.x;
    if (tid < 32) {
        const int b = tid >> 2, s = tid & 3;
        float c = 0.f;
        for (int t = 0; t < 64; ++t) c += (sid[b * 64 + t] == s) ? 1.f : 0.f;
        counts[tid] = c;
    }
}

// d_out = [X (25165824 f32) | M (24576 f32)]
__global__ __launch_bounds__(256)
void final_out(const u16* __restrict__ Xb, const float* __restrict__ M,
               float* __restrict__ out)
{
    const size_t i = (size_t)blockIdx.x * 256 + threadIdx.x;
    const size_t NX = 25165824ull;
    if (i < NX) out[i] = b2f(Xb[i]);
    else if (i < NX + 24576ull) out[i] = M[i - NX];
}

// ---------------------------------------------------------------------------
extern "C" void kernel_launch(void* const* d_in, const int* in_sizes, int n_in,
                              void* d_out, int out_size, void* d_ws, size_t ws_size,
                              hipStream_t stream)
{
    const int*   input_ids = (const int*)d_in[0];
    const int*   attn_mask = (const int*)d_in[1];
    const int*   sid       = (const int*)d_in[2];
    const float* tok_emb   = (const float*)d_in[3];
    const float* pos_emb   = (const float*)d_in[4];
    const float* turn_emb  = (const float*)d_in[5];
    const float* mha_in_w  = (const float*)d_in[6];
    const float* mha_in_b  = (const float*)d_in[7];
    const float* mha_out_w = (const float*)d_in[8];
    const float* mha_out_b = (const float*)d_in[9];
    const float* ffn_w1    = (const float*)d_in[10];
    const float* ffn_b1    = (const float*)d_in[11];
    const float* ffn_w2    = (const float*)d_in[12];
    const float* ffn_b2    = (const float*)d_in[13];
    const float* ln1_g     = (const float*)d_in[14];
    const float* ln1_b     = (const float*)d_in[15];
    const float* ln2_g     = (const float*)d_in[16];
    const float* ln2_b     = (const float*)d_in[17];
    const float* gate_w    = (const float*)d_in[18];
    const float* gate_b    = (const float*)d_in[19];
    const float* sn_g      = (const float*)d_in[20];
    const float* sn_b      = (const float*)d_in[21];
    const float* ca_in_w   = (const float*)d_in[22];
    const float* ca_in_b   = (const float*)d_in[23];
    const float* ca_out_w  = (const float*)d_in[24];
    const float* ca_out_b  = (const float*)d_in[25];
    (void)in_sizes; (void)n_in; (void)out_size;

    // -------- adaptive plan based on ws_size --------
    const size_t MB = 1ull << 20;
    int NCA, NCF; bool allW;
    if      (ws_size >= 460 * MB) { NCA = 2; NCF = 1; allW = true;  }  // Plan A
    else if (ws_size >= 255 * MB) { NCA = 2; NCF = 2; allW = false; }  // Plan B
    else                          { NCA = 4; NCF = 4; allW = false; }  // Plan C
    const int MRA = 32768 / NCA;
    const int MRF = 32768 / NCF;
    const size_t wl = allW ? 4 : 1;

    char* p = (char*)d_ws;
    auto alloc = [&](size_t n) { void* r = p; p += (n + 255) & ~(size_t)255; return r; };
    u16*   Xb    = (u16*)alloc(50331648);
    u16*   Hb    = (u16*)alloc(50331648);
    u16*   WqkvT = (u16*)alloc(wl * 3538944);
    u16*   WoT   = (u16*)alloc(wl * 1179648);
    u16*   W1T   = (u16*)alloc(wl * 4718592);
    u16*   W2T   = (u16*)alloc(wl * 4718592);
    u16*   WgT   = (u16*)alloc(wl * 3538944);
    u16*   WcaT  = (u16*)alloc(wl * 3538944);
    u16*   WcoT  = (u16*)alloc(wl * 1179648);
    float* mt    = (float*)alloc(1572864);
    u16*   tcb   = (u16*)alloc(786432);
    u16*   Mb    = (u16*)alloc(49152);
    u16*   qc    = (u16*)alloc(786432);
    u16*   kvc   = (u16*)alloc(98304);
    u16*   cca   = (u16*)alloc(786432);
    u16*   ccp   = (u16*)alloc(786432);
    u16*   Fu    = (u16*)alloc(2359296);
    float* gout  = (float*)alloc(1572864);
    float* upd   = (float*)alloc(1572864);
    float* cnts  = (float*)alloc(256);
    float* M     = (float*)alloc(98304);

    u16 *A, *QKVb, *Gb;
    if (NCF == 1) {          // Plan A
        A    = (u16*)alloc(50331648);
        Gb   = (u16*)alloc(201326592);
        QKVb = (u16*)d_out;
    } else if (NCF == 2) {   // Plan B
        A    = (u16*)alloc(50331648);
        QKVb = (u16*)alloc((size_t)MRA * 2304 * 2);
        Gb   = (u16*)d_out;
    } else {                 // Plan C
        Gb   = (u16*)alloc((size_t)MRF * 3072 * 2);
        A    = (u16*)d_out;
        QKVb = (u16*)d_out + 25165824;
    }
    u16* Obuf = Gb;

    zero_f32<<<96, 256, 0, stream>>>(M, 24576);
    calc_counts<<<1, 64, 0, stream>>>(sid, cnts);
    embed_k<<<32768, 192, 0, stream>>>(input_ids, tok_emb, pos_emb, turn_emb, Xb);

    if (allW) {
        transp_conv<<<dim3(72, 24, 4), dim3(32, 8), 0, stream>>>(mha_in_w,  WqkvT, 768, 2304);
        transp_conv<<<dim3(24, 24, 4), dim3(32, 8), 0, stream>>>(mha_out_w, WoT,   768, 768);
        transp_conv<<<dim3(96, 24, 4), dim3(32, 8), 0, stream>>>(ffn_w1,    W1T,   768, 3072);
        transp_conv<<<dim3(24, 96, 4), dim3(32, 8), 0, stream>>>(ffn_w2,    W2T,  3072, 768);
        transp_conv<<<dim3(24, 72, 4), dim3(32, 8), 0, stream>>>(gate_w,    WgT,  2304, 768);
        transp_conv<<<dim3(72, 24, 4), dim3(32, 8), 0, stream>>>(ca_in_w,   WcaT,  768, 2304);
        transp_conv<<<dim3(24, 24, 4), dim3(32, 8), 0, stream>>>(ca_out_w,  WcoT,  768, 768);
    }

    for (int l = 0; l < 4; ++l) {
        if (!allW) {
            transp_conv<<<dim3(72, 24), dim3(32, 8), 0, stream>>>(mha_in_w  + (size_t)l * 768 * 2304, WqkvT, 768, 2304);
            transp_conv<<<dim3(24, 24), dim3(32, 8), 0, stream>>>(mha_out_w + (size_t)l * 768 * 768,  WoT,   768, 768);
            transp_conv<<<dim3(96, 24), dim3(32, 8), 0, stream>>>(ffn_w1    + (size_t)l * 768 * 3072, W1T,   768, 3072);
            transp_conv<<<dim3(24, 96), dim3(32, 8), 0, stream>>>(ffn_w2    + (size_t)l * 3072 * 768, W2T,  3072, 768);
            transp_conv<<<dim3(24, 72), dim3(32, 8), 0, stream>>>(gate_w    + (size_t)l * 2304 * 768, WgT,  2304, 768);
            transp_conv<<<dim3(72, 24), dim3(32, 8), 0, stream>>>(ca_in_w   + (size_t)l * 768 * 2304, WcaT,  768, 2304);
            transp_conv<<<dim3(24, 24), dim3(32, 8), 0, stream>>>(ca_out_w  + (size_t)l * 768 * 768,  WcoT,  768, 768);
        }
        const u16* Wqkv_l = WqkvT + (size_t)(allW ? l : 0) * 2304 * 768;
        const u16* Wo_l   = WoT   + (size_t)(allW ? l : 0) * 768 * 768;
        const u16* W1_l   = W1T   + (size_t)(allW ? l : 0) * 768 * 3072;
        const u16* W2_l   = W2T   + (size_t)(allW ? l : 0) * 3072 * 768;
        const u16* Wg_l   = WgT   + (size_t)(allW ? l : 0) * 2304 * 768;
        const u16* Wca_l  = WcaT  + (size_t)(allW ? l : 0) * 768 * 2304;
        const u16* Wco_l  = WcoT  + (size_t)(allW ? l : 0) * 768 * 768;

        gather_mt<<<512, 256, 0, stream>>>(M, sid, mt);
        prep_ain<<<32768, 192, 0, stream>>>(Xb, mt, attn_mask, A);

        for (int c = 0; c < NCA; ++c) {
            u16* Ac = A + (size_t)c * MRA * 768;
            gemm_bt<0><<<dim3(18, MRA / 128), 256, 0, stream>>>(Ac, Wqkv_l, mha_in_b + l * 2304, QKVb, MRA, 2304, 768);
            attn_self<<<(MRA / 64) * 12, 256, 0, stream>>>(QKVb, Obuf);
            gemm_bt<0><<<dim3(6, MRA / 128), 256, 0, stream>>>(Obuf, Wo_l, mha_out_b + l * 768, Ac, MRA, 768, 768);
        }
        ln_res<<<32768, 256, 0, stream>>>(A, Xb, ln1_g + l * 768, ln1_b + l * 768, Hb);

        for (int c = 0; c < NCF; ++c) {
            u16* Hc = Hb + (size_t)c * MRF * 768;
            u16* Ac = A  + (size_t)c * MRF * 768;
            gemm_bt<1><<<dim3(24, MRF / 128), 256, 0, stream>>>(Hc, W1_l, ffn_b1 + l * 3072, Gb, MRF, 3072, 768);
            gemm_bt<0><<<dim3(6, MRF / 128), 256, 0, stream>>>(Gb, W2_l, ffn_b2 + l * 768, Ac, MRF, 768, 3072);
        }
        ln_res<<<32768, 256, 0, stream>>>(A, Hb, ln2_g + l * 768, ln2_b + l * 768, Xb);

        tc_mean<<<512, 256, 0, stream>>>(Xb, tcb);
        conv_bf16<<<96, 256, 0, stream>>>(M, Mb, 24576);
        gemm_bt<0><<<dim3(6, 4), 256, 0, stream>>>(tcb, Wca_l, ca_in_b + l * 2304, qc, 512, 768, 768);
        gemm_bt<0><<<dim3(12, 1), 256, 0, stream>>>(Mb, Wca_l + 768 * 768, ca_in_b + l * 2304 + 768, kvc, 32, 1536, 768);
        cross_attn<<<512, 256, 0, stream>>>(qc, kvc, cca);
        gemm_bt<0><<<dim3(6, 4), 256, 0, stream>>>(cca, Wco_l, ca_out_b + l * 768, ccp, 512, 768, 768);
        concat_fused<<<512, 256, 0, stream>>>(tcb, mt, ccp, Fu);
        gemm_bt<2><<<dim3(6, 4), 256, 0, stream>>>(Fu, Wg_l, gate_b + l * 768, gout, 512, 768, 2304);
        ln_upd<<<512, 256, 0, stream>>>(gout, mt, sn_g + l * 768, sn_b + l * 768, upd);
        scatter_mem<<<32, 256, 0, stream>>>(upd, sid, cnts, M);
    }

    final_out<<<98400, 256, 0, stream>>>(Xb, M, (float*)d_out);
}

// Round 7
// 4067.013 us; speedup vs baseline: 1.0525x; 1.0525x over previous
//
#include <hip/hip_runtime.h>

using u16 = unsigned short;
using u32 = unsigned int;

#define DI __device__ __forceinline__

typedef __bf16 bf16x8 __attribute__((ext_vector_type(8)));
typedef float  f32x4  __attribute__((ext_vector_type(4)));

DI float b2f(u16 u){ u32 x = ((u32)u) << 16; float f; __builtin_memcpy(&f, &x, 4); return f; }
// native RNE f32->bf16 (compiler emits v_cvt_pk_bf16_f32)
DI u16 f2b(float f){ __bf16 h = (__bf16)f; u16 r; __builtin_memcpy(&r, &h, 2); return r; }
// tanh-form GELU: |err vs erf-GELU| <= ~5e-4 absolute
DI float gelu_fast(float v){
    float u = v * (0.7978845608f + 0.0356774081f * v * v);
    float e = __expf(2.0f * u);
    float t = 1.0f - 2.0f / (e + 1.0f);
    return 0.5f * v * (1.0f + t);
}

#define GLOAD16(g, l) __builtin_amdgcn_global_load_lds( \
    (const __attribute__((address_space(1))) void*)(g), \
    (__attribute__((address_space(3))) void*)(l), 16, 0, 0)

// inline-asm LDS read: opaque to the compiler's alias analysis, so it cannot
// insert its own conservative s_waitcnt vmcnt(0) against in-flight
// global_load_lds ops. Caller must issue s_waitcnt lgkmcnt(0) + sched_barrier.
DI bf16x8 ldsr128(const u16* p) {
    bf16x8 r;
    asm volatile("ds_read_b128 %0, %1"
                 : "=v"(r)
                 : "v"((const __attribute__((address_space(3))) u16*)p));
    return r;
}

// ---------------------------------------------------------------------------
// Generic bf16 GEMM:  C[M][N] = A[M][K] @ Bt[N][K]^T + bias
// Triple-buffered, prefetch distance 2, counted vmcnt(4); fragment loads via
// inline-asm ds_read_b128 so the counted vmcnt actually governs (no compiler
// drain). lgkmcnt(0)+sched_barrier(0) before MFMA (rule #18).
// EPI: 0 = bias, store bf16; 1 = bias+GELU, store bf16; 2 = bias, store f32
// ---------------------------------------------------------------------------
template<int EPI>
__global__ __launch_bounds__(256)
void gemm_bt(const u16* __restrict__ A, const u16* __restrict__ Bt,
             const float* __restrict__ bias, void* __restrict__ Cout,
             int M, int N, int K)
{
    __shared__ u16 lA[3][128 * 32];
    __shared__ u16 lB[3][128 * 32];
    const int tid  = threadIdx.x;
    const int lane = tid & 63;
    const int w    = tid >> 6;
    const int wm   = w >> 1, wn = w & 1;

    const int nx = gridDim.x;
    const int nb = nx * gridDim.y;
    int bid = blockIdx.y * nx + blockIdx.x;
    if ((nb & 7) == 0) bid = ((bid & 7) * (nb >> 3)) + (bid >> 3);
    const int m0 = (bid / nx) * 128;
    const int n0 = (bid % nx) * 128;

    f32x4 acc[4][4] = {};

    const int srow = tid >> 2;                                  // 0..63
    const int scol = (((tid & 3) ^ ((tid >> 3) & 3)) * 8);      // inverse-swizzled source chunk
    int ar0 = m0 + srow;      if (ar0 > M - 1) ar0 = M - 1;
    int ar1 = m0 + 64 + srow; if (ar1 > M - 1) ar1 = M - 1;
    const u16* gA0 = A  + (size_t)ar0 * K + scol;
    const u16* gA1 = A  + (size_t)ar1 * K + scol;
    const u16* gB0 = Bt + (size_t)(n0 + srow) * K + scol;
    const u16* gB1 = Bt + (size_t)(n0 + 64 + srow) * K + scol;

    const int la = lane & 15, lg = lane >> 4;
    const int cp = (lg ^ ((la >> 1) & 3)) * 8;                  // swizzled read chunk

    const int nt = K >> 5;

    // prologue: stage tiles 0 and 1 (8 loads in flight)
    GLOAD16(gA0,      &lA[0][tid * 8]);
    GLOAD16(gA1,      &lA[0][tid * 8 + 2048]);
    GLOAD16(gB0,      &lB[0][tid * 8]);
    GLOAD16(gB1,      &lB[0][tid * 8 + 2048]);
    GLOAD16(gA0 + 32, &lA[1][tid * 8]);
    GLOAD16(gA1 + 32, &lA[1][tid * 8 + 2048]);
    GLOAD16(gB0 + 32, &lB[1][tid * 8]);
    GLOAD16(gB1 + 32, &lB[1][tid * 8 + 2048]);

    int cur = 0, pre = 2;       // buffer indices: read cur, stage into pre
    for (int t = 0; t < nt; ++t) {
        // wait for tile t only; tile t+1's 4 loads remain in flight
        if (t + 1 < nt) asm volatile("s_waitcnt vmcnt(4)" ::: "memory");
        else            asm volatile("s_waitcnt vmcnt(0)" ::: "memory");
        __builtin_amdgcn_s_barrier();
        asm volatile("" ::: "memory");

        if (t + 2 < nt) {       // stage tile t+2 (buffer last read in iter t-1,
            const int k0 = (t + 2) << 5;  // fully consumed before barrier t)
            GLOAD16(gA0 + k0, &lA[pre][tid * 8]);
            GLOAD16(gA1 + k0, &lA[pre][tid * 8 + 2048]);
            GLOAD16(gB0 + k0, &lB[pre][tid * 8]);
            GLOAD16(gB1 + k0, &lB[pre][tid * 8 + 2048]);
        }

        bf16x8 af[4], bfr[4];
        #pragma unroll
        for (int i = 0; i < 4; i++)
            af[i] = ldsr128(&lA[cur][(wm * 64 + i * 16 + la) * 32 + cp]);
        #pragma unroll
        for (int j = 0; j < 4; j++)
            bfr[j] = ldsr128(&lB[cur][(wn * 64 + j * 16 + la) * 32 + cp]);
        asm volatile("s_waitcnt lgkmcnt(0)" ::: "memory");
        __builtin_amdgcn_sched_barrier(0);

        #pragma unroll
        for (int i = 0; i < 4; i++)
            #pragma unroll
            for (int j = 0; j < 4; j++)
                acc[i][j] = __builtin_amdgcn_mfma_f32_16x16x32_bf16(af[i], bfr[j], acc[i][j], 0, 0, 0);

        cur = (cur == 2) ? 0 : cur + 1;
        pre = (pre == 2) ? 0 : pre + 1;
    }

    #pragma unroll
    for (int i = 0; i < 4; i++) {
        const int rowb = m0 + wm * 64 + i * 16 + lg * 4;
        #pragma unroll
        for (int j = 0; j < 4; j++) {
            const int col = n0 + wn * 64 + j * 16 + la;
            const float bv = bias[col];
            #pragma unroll
            for (int r = 0; r < 4; r++) {
                const int rr = rowb + r;
                if (rr < M) {
                    float v = acc[i][j][r] + bv;
                    if constexpr (EPI == 1) v = gelu_fast(v);
                    if constexpr (EPI == 2) ((float*)Cout)[(size_t)rr * N + col] = v;
                    else                    ((u16*)Cout)[(size_t)rr * N + col] = f2b(v);
                }
            }
        }
    }
}

// ---------------------------------------------------------------------------
// fp32 [z][K][N] -> bf16 [z][N][K] transpose-convert
// ---------------------------------------------------------------------------
__global__ __launch_bounds__(256)
void transp_conv(const float* __restrict__ in, u16* __restrict__ out, int K, int N)
{
    __shared__ float tile[32][33];
    const int l = blockIdx.z;
    const float* inp = in + (size_t)l * K * N;
    u16* op = out + (size_t)l * K * N;
    const int kb = blockIdx.y * 32, nb = blockIdx.x * 32;
    const int tx = threadIdx.x, ty = threadIdx.y;
    #pragma unroll
    for (int i = 0; i < 32; i += 8)
        tile[ty + i][tx] = inp[(size_t)(kb + ty + i) * N + nb + tx];
    __syncthreads();
    #pragma unroll
    for (int i = 0; i < 32; i += 8)
        op[(size_t)(nb + ty + i) * K + kb + tx] = f2b(tile[tx][ty + i]);
}

// ---------------------------------------------------------------------------
// Embedding
// ---------------------------------------------------------------------------
__global__ __launch_bounds__(192)
void embed_k(const int* __restrict__ ids, const float* __restrict__ te,
             const float* __restrict__ pe, const float* __restrict__ ue,
             u16* __restrict__ X)
{
    const int tok = blockIdx.x;
    const int l = tok & 63;
    const int t = (tok >> 6) & 63;
    const int id = ids[tok];
    const int c = threadIdx.x * 4;
    float4 a = *(const float4*)&te[(size_t)id * 768 + c];
    float4 p = *(const float4*)&pe[(size_t)l * 768 + c];
    float4 u = *(const float4*)&ue[(size_t)t * 768 + c];
    ushort4 o;
    o.x = f2b(a.x + p.x + u.x); o.y = f2b(a.y + p.y + u.y);
    o.z = f2b(a.z + p.z + u.z); o.w = f2b(a.w + p.w + u.w);
    *(ushort4*)&X[(size_t)tok * 768 + c] = o;
}

// m_t gather: mt[bt] = M[b, sid[bt]]
__global__ __launch_bounds__(256)
void gather_mt(const float* __restrict__ M, const int* __restrict__ sid,
               float* __restrict__ mt)
{
    const int bt = blockIdx.x, b = bt >> 6, tid = threadIdx.x;
    const float* src = M + ((size_t)b * 4 + sid[bt]) * 768;
    float* dst = mt + (size_t)bt * 768;
    dst[tid] = src[tid]; dst[tid + 256] = src[tid + 256]; dst[tid + 512] = src[tid + 512];
}

// Ain = (X + mt[bt]) * mask  (bf16 out)
__global__ __launch_bounds__(192)
void prep_ain(const u16* __restrict__ X, const float* __restrict__ mt,
              const int* __restrict__ mask, u16* __restrict__ Ain)
{
    const int tok = blockIdx.x, bt = tok >> 6;
    const float mk = (float)mask[tok];
    const int c = threadIdx.x * 4;
    ushort4 xv = *(const ushort4*)&X[(size_t)tok * 768 + c];
    float4 mv = *(const float4*)&mt[(size_t)bt * 768 + c];
    ushort4 o;
    o.x = f2b((b2f(xv.x) + mv.x) * mk); o.y = f2b((b2f(xv.y) + mv.y) * mk);
    o.z = f2b((b2f(xv.z) + mv.z) * mk); o.w = f2b((b2f(xv.w) + mv.w) * mk);
    *(ushort4*)&Ain[(size_t)tok * 768 + c] = o;
}

// ---------------------------------------------------------------------------
// Self-attention per (bt_local, head). XOR-swizzled LDS (write+read involution).
// ---------------------------------------------------------------------------
DI int swz(int row, int col) { return row * 64 + (((col >> 3) ^ (row & 7)) << 3) + (col & 7); }

__global__ __launch_bounds__(256)
void attn_self(const u16* __restrict__ QKV, u16* __restrict__ O)
{
    __shared__ u16 lQ[64 * 64], lK[64 * 64], lVt[64 * 64], lP[64 * 64];
    __shared__ float lS[64 * 68];
    const int bt = blockIdx.x / 12, h = blockIdx.x % 12;
    const int tid = threadIdx.x, lane = tid & 63, w = tid >> 6;
    const size_t base = (size_t)bt * 64 * 2304;

    #pragma unroll
    for (int it = 0; it < 2; ++it) {
        const int slot = it * 256 + tid;
        const int l = slot >> 3, dc = (slot & 7) * 8;
        const u16* qp = QKV + base + (size_t)l * 2304 + h * 64 + dc;
        *(uint4*)&lQ[swz(l, dc)] = *(const uint4*)qp;
        *(uint4*)&lK[swz(l, dc)] = *(const uint4*)(qp + 768);
        uint4 vv = *(const uint4*)(qp + 1536);
        u16 tmp[8]; *(uint4*)tmp = vv;
        #pragma unroll
        for (int j = 0; j < 8; j++) lVt[swz(dc + j, l)] = tmp[j];
    }
    __syncthreads();

    const int la = lane & 15, lg = lane >> 4;
    {   // s = Q K^T / 8 ; wave w owns q-rows [w*16, w*16+16)
        f32x4 sa[4] = {};
        #pragma unroll
        for (int kh = 0; kh < 64; kh += 32) {
            bf16x8 aq = *(const bf16x8*)&lQ[swz(w * 16 + la, kh + lg * 8)];
            #pragma unroll
            for (int fn = 0; fn < 4; ++fn) {
                bf16x8 bk = *(const bf16x8*)&lK[swz(fn * 16 + la, kh + lg * 8)];
                sa[fn] = __builtin_amdgcn_mfma_f32_16x16x32_bf16(aq, bk, sa[fn], 0, 0, 0);
            }
        }
        #pragma unroll
        for (int fn = 0; fn < 4; ++fn)
            #pragma unroll
            for (int r = 0; r < 4; ++r)
                lS[(w * 16 + lg * 4 + r) * 68 + fn * 16 + la] = sa[fn][r] * 0.125f;
    }
    __syncthreads();

    {   // softmax over k (row = q), 4 lanes per row
        const int row = tid >> 2, q4 = tid & 3;
        float e[16]; float mx = -1e30f;
        #pragma unroll
        for (int j = 0; j < 16; j++) { e[j] = lS[row * 68 + q4 * 16 + j]; mx = fmaxf(mx, e[j]); }
        mx = fmaxf(mx, __shfl_xor(mx, 1)); mx = fmaxf(mx, __shfl_xor(mx, 2));
        float sm = 0.f;
        #pragma unroll
        for (int j = 0; j < 16; j++) { e[j] = __expf(e[j] - mx); sm += e[j]; }
        sm += __shfl_xor(sm, 1); sm += __shfl_xor(sm, 2);
        const float inv = 1.0f / sm;
        #pragma unroll
        for (int j = 0; j < 16; j++) lP[swz(row, q4 * 16 + j)] = f2b(e[j] * inv);
    }
    __syncthreads();

    {   // O = P V
        f32x4 oa[4] = {};
        #pragma unroll
        for (int kh = 0; kh < 64; kh += 32) {
            bf16x8 ap = *(const bf16x8*)&lP[swz(w * 16 + la, kh + lg * 8)];
            #pragma unroll
            for (int fn = 0; fn < 4; ++fn) {
                bf16x8 bv = *(const bf16x8*)&lVt[swz(fn * 16 + la, kh + lg * 8)];
                oa[fn] = __builtin_amdgcn_mfma_f32_16x16x32_bf16(ap, bv, oa[fn], 0, 0, 0);
            }
        }
        const size_t ob = (size_t)bt * 64 * 768 + h * 64;
        #pragma unroll
        for (int fn = 0; fn < 4; ++fn)
            #pragma unroll
            for (int r = 0; r < 4; ++r)
                O[ob + (size_t)(w * 16 + lg * 4 + r) * 768 + fn * 16 + la] = f2b(oa[fn][r]);
    }
}

DI float wave_red(float v) {
    #pragma unroll
    for (int o = 32; o > 0; o >>= 1) v += __shfl_xor(v, o);
    return v;
}

// LN over H=768 of (a + b), bf16 in, bf16 out; grid = rows
__global__ __launch_bounds__(256)
void ln_res(const u16* __restrict__ a, const u16* __restrict__ b,
            const float* __restrict__ g, const float* __restrict__ be,
            u16* __restrict__ out)
{
    __shared__ float red[8];
    const int tid = threadIdx.x;
    const size_t off = (size_t)blockIdx.x * 768;
    float x0 = b2f(a[off + tid])       + b2f(b[off + tid]);
    float x1 = b2f(a[off + tid + 256]) + b2f(b[off + tid + 256]);
    float x2 = b2f(a[off + tid + 512]) + b2f(b[off + tid + 512]);
    float s = wave_red(x0 + x1 + x2);
    float ss = wave_red(x0 * x0 + x1 * x1 + x2 * x2);
    if ((tid & 63) == 0) { red[tid >> 6] = s; red[4 + (tid >> 6)] = ss; }
    __syncthreads();
    s = red[0] + red[1] + red[2] + red[3];
    ss = red[4] + red[5] + red[6] + red[7];
    const float mean = s * (1.f / 768.f);
    const float var = fmaxf(ss * (1.f / 768.f) - mean * mean, 0.f);
    const float inv = rsqrtf(var + 1e-5f);
    out[off + tid]       = f2b((x0 - mean) * inv * g[tid]       + be[tid]);
    out[off + tid + 256] = f2b((x1 - mean) * inv * g[tid + 256] + be[tid + 256]);
    out[off + tid + 512] = f2b((x2 - mean) * inv * g[tid + 512] + be[tid + 512]);
}

// LN over H=768 of (a + b), f32 in, f32 out
__global__ __launch_bounds__(256)
void ln_upd(const float* __restrict__ a, const float* __restrict__ b,
            const float* __restrict__ g, const float* __restrict__ be,
            float* __restrict__ out)
{
    __shared__ float red[8];
    const int tid = threadIdx.x;
    const size_t off = (size_t)blockIdx.x * 768;
    float x0 = a[off + tid]       + b[off + tid];
    float x1 = a[off + tid + 256] + b[off + tid + 256];
    float x2 = a[off + tid + 512] + b[off + tid + 512];
    float s = wave_red(x0 + x1 + x2);
    float ss = wave_red(x0 * x0 + x1 * x1 + x2 * x2);
    if ((tid & 63) == 0) { red[tid >> 6] = s; red[4 + (tid >> 6)] = ss; }
    __syncthreads();
    s = red[0] + red[1] + red[2] + red[3];
    ss = red[4] + red[5] + red[6] + red[7];
    const float mean = s * (1.f / 768.f);
    const float var = fmaxf(ss * (1.f / 768.f) - mean * mean, 0.f);
    const float inv = rsqrtf(var + 1e-5f);
    out[off + tid]       = (x0 - mean) * inv * g[tid]       + be[tid];
    out[off + tid + 256] = (x1 - mean) * inv * g[tid + 256] + be[tid + 256];
    out[off + tid + 512] = (x2 - mean) * inv * g[tid + 512] + be[tid + 512];
}

// tc = mean over L of X ; grid 512 (bt)
__global__ __launch_bounds__(256)
void tc_mean(const u16* __restrict__ X, u16* __restrict__ tcb)
{
    const int bt = blockIdx.x, tid = threadIdx.x;
    float s0 = 0, s1 = 0, s2 = 0;
    for (int l = 0; l < 64; ++l) {
        const u16* r = X + ((size_t)bt * 64 + l) * 768;
        s0 += b2f(r[tid]); s1 += b2f(r[tid + 256]); s2 += b2f(r[tid + 512]);
    }
    tcb[(size_t)bt * 768 + tid]       = f2b(s0 * (1.f / 64.f));
    tcb[(size_t)bt * 768 + tid + 256] = f2b(s1 * (1.f / 64.f));
    tcb[(size_t)bt * 768 + tid + 512] = f2b(s2 * (1.f / 64.f));
}

// f32 -> bf16 convert
__global__ __launch_bounds__(256)
void conv_bf16(const float* __restrict__ in, u16* __restrict__ out, int n)
{
    const int i = blockIdx.x * 256 + threadIdx.x;
    if (i < n) out[i] = f2b(in[i]);
}

// zero f32 buffer
__global__ __launch_bounds__(256)
void zero_f32(float* __restrict__ buf, int n)
{
    const int i = blockIdx.x * 256 + threadIdx.x;
    if (i < n) buf[i] = 0.f;
}

// cross-attention per (b,t): 4 heads over S=4 speakers; grid 512
__global__ __launch_bounds__(256)
void cross_attn(const u16* __restrict__ qc, const u16* __restrict__ kvc,
                u16* __restrict__ cca)
{
    __shared__ float q[768], kk[4][768], vv[4][768], sraw[16], aw[16];
    const int bt = blockIdx.x, b = bt >> 6, tid = threadIdx.x;
    #pragma unroll
    for (int i = 0; i < 3; i++) q[tid + i * 256] = b2f(qc[(size_t)bt * 768 + tid + i * 256]);
    #pragma unroll
    for (int i = 0; i < 12; i++) {
        const int idx = i * 256 + tid;
        const int s = idx / 768, d = idx % 768;
        kk[s][d] = b2f(kvc[(size_t)(b * 4 + s) * 1536 + d]);
        vv[s][d] = b2f(kvc[(size_t)(b * 4 + s) * 1536 + 768 + d]);
    }
    __syncthreads();
    if (tid < 16) {
        const int hh = tid >> 2, s = tid & 3;
        float acc = 0.f;
        for (int d = 0; d < 192; ++d) acc += q[hh * 192 + d] * kk[s][hh * 192 + d];
        sraw[tid] = acc * 0.07216878364870323f; // 1/sqrt(192)
    }
    __syncthreads();
    if (tid < 4) {
        float m = -1e30f;
        for (int s = 0; s < 4; s++) m = fmaxf(m, sraw[tid * 4 + s]);
        float ee[4], sm = 0.f;
        for (int s = 0; s < 4; s++) { ee[s] = __expf(sraw[tid * 4 + s] - m); sm += ee[s]; }
        for (int s = 0; s < 4; s++) aw[tid * 4 + s] = ee[s] / sm;
    }
    __syncthreads();
    #pragma unroll
    for (int i = 0; i < 3; i++) {
        const int j = tid + i * 256;
        const int hh = j / 192;
        float v = aw[hh * 4 + 0] * vv[0][j] + aw[hh * 4 + 1] * vv[1][j]
                + aw[hh * 4 + 2] * vv[2][j] + aw[hh * 4 + 3] * vv[3][j];
        cca[(size_t)bt * 768 + j] = f2b(v);
    }
}

// fused = [tc | m_t | cc]  bf16, grid 512
__global__ __launch_bounds__(256)
void concat_fused(const u16* __restrict__ tcb, const float* __restrict__ mt,
                  const u16* __restrict__ ccp, u16* __restrict__ Fu)
{
    const int bt = blockIdx.x, tid = threadIdx.x;
    u16* o = Fu + (size_t)bt * 2304;
    #pragma unroll
    for (int i = 0; i < 3; i++) {
        const int j = tid + i * 256;
        o[j]        = tcb[(size_t)bt * 768 + j];
        o[768 + j]  = f2b(mt[(size_t)bt * 768 + j]);
        o[1536 + j] = ccp[(size_t)bt * 768 + j];
    }
}

// per-(b,s) mean of upd over that speaker's turns; grid 32
__global__ __launch_bounds__(256)
void scatter_mem(const float* __restrict__ upd, const int* __restrict__ sid,
                 const float* __restrict__ counts, float* __restrict__ M)
{
    const int bs = blockIdx.x, b = bs >> 2, s = bs & 3, tid = threadIdx.x;
    const float c = counts[bs];
    #pragma unroll
    for (int i = 0; i < 3; i++) {
        const int j = tid + i * 256;
        float acc = 0.f;
        for (int t = 0; t < 64; ++t)
            if (sid[b * 64 + t] == s) acc += upd[((size_t)b * 64 + t) * 768 + j];
        if (c > 0.f) M[(size_t)bs * 768 + j] = acc / fmaxf(c, 1.f);
    }
}

__global__ void calc_counts(const int* __restrict__ sid, float* __restrict__ counts)
{
    const int tid = threadIdx.x;
    if (tid < 32) {
        const int b = tid >> 2, s = tid & 3;
        float c = 0.f;
        for (int t = 0; t < 64; ++t) c += (sid[b * 64 + t] == s) ? 1.f : 0.f;
        counts[tid] = c;
    }
}

// d_out = [X (25165824 f32) | M (24576 f32)]
__global__ __launch_bounds__(256)
void final_out(const u16* __restrict__ Xb, const float* __restrict__ M,
               float* __restrict__ out)
{
    const size_t i = (size_t)blockIdx.x * 256 + threadIdx.x;
    const size_t NX = 25165824ull;
    if (i < NX) out[i] = b2f(Xb[i]);
    else if (i < NX + 24576ull) out[i] = M[i - NX];
}

// ---------------------------------------------------------------------------
extern "C" void kernel_launch(void* const* d_in, const int* in_sizes, int n_in,
                              void* d_out, int out_size, void* d_ws, size_t ws_size,
                              hipStream_t stream)
{
    const int*   input_ids = (const int*)d_in[0];
    const int*   attn_mask = (const int*)d_in[1];
    const int*   sid       = (const int*)d_in[2];
    const float* tok_emb   = (const float*)d_in[3];
    const float* pos_emb   = (const float*)d_in[4];
    const float* turn_emb  = (const float*)d_in[5];
    const float* mha_in_w  = (const float*)d_in[6];
    const float* mha_in_b  = (const float*)d_in[7];
    const float* mha_out_w = (const float*)d_in[8];
    const float* mha_out_b = (const float*)d_in[9];
    const float* ffn_w1    = (const float*)d_in[10];
    const float* ffn_b1    = (const float*)d_in[11];
    const float* ffn_w2    = (const float*)d_in[12];
    const float* ffn_b2    = (const float*)d_in[13];
    const float* ln1_g     = (const float*)d_in[14];
    const float* ln1_b     = (const float*)d_in[15];
    const float* ln2_g     = (const float*)d_in[16];
    const float* ln2_b     = (const float*)d_in[17];
    const float* gate_w    = (const float*)d_in[18];
    const float* gate_b    = (const float*)d_in[19];
    const float* sn_g      = (const float*)d_in[20];
    const float* sn_b      = (const float*)d_in[21];
    const float* ca_in_w   = (const float*)d_in[22];
    const float* ca_in_b   = (const float*)d_in[23];
    const float* ca_out_w  = (const float*)d_in[24];
    const float* ca_out_b  = (const float*)d_in[25];
    (void)in_sizes; (void)n_in; (void)out_size;

    // -------- adaptive plan based on ws_size --------
    const size_t MB = 1ull << 20;
    int NCA, NCF; bool allW;
    if      (ws_size >= 460 * MB) { NCA = 2; NCF = 1; allW = true;  }  // Plan A
    else if (ws_size >= 255 * MB) { NCA = 2; NCF = 2; allW = false; }  // Plan B
    else                          { NCA = 4; NCF = 4; allW = false; }  // Plan C
    const int MRA = 32768 / NCA;
    const int MRF = 32768 / NCF;
    const size_t wl = allW ? 4 : 1;

    char* p = (char*)d_ws;
    auto alloc = [&](size_t n) { void* r = p; p += (n + 255) & ~(size_t)255; return r; };
    u16*   Xb    = (u16*)alloc(50331648);
    u16*   Hb    = (u16*)alloc(50331648);
    u16*   WqkvT = (u16*)alloc(wl * 3538944);
    u16*   WoT   = (u16*)alloc(wl * 1179648);
    u16*   W1T   = (u16*)alloc(wl * 4718592);
    u16*   W2T   = (u16*)alloc(wl * 4718592);
    u16*   WgT   = (u16*)alloc(wl * 3538944);
    u16*   WcaT  = (u16*)alloc(wl * 3538944);
    u16*   WcoT  = (u16*)alloc(wl * 1179648);
    float* mt    = (float*)alloc(1572864);
    u16*   tcb   = (u16*)alloc(786432);
    u16*   Mb    = (u16*)alloc(49152);
    u16*   qc    = (u16*)alloc(786432);
    u16*   kvc   = (u16*)alloc(98304);
    u16*   cca   = (u16*)alloc(786432);
    u16*   ccp   = (u16*)alloc(786432);
    u16*   Fu    = (u16*)alloc(2359296);
    float* gout  = (float*)alloc(1572864);
    float* upd   = (float*)alloc(1572864);
    float* cnts  = (float*)alloc(256);
    float* M     = (float*)alloc(98304);

    u16 *A, *QKVb, *Gb;
    if (NCF == 1) {          // Plan A
        A    = (u16*)alloc(50331648);
        Gb   = (u16*)alloc(201326592);
        QKVb = (u16*)d_out;
    } else if (NCF == 2) {   // Plan B
        A    = (u16*)alloc(50331648);
        QKVb = (u16*)alloc((size_t)MRA * 2304 * 2);
        Gb   = (u16*)d_out;
    } else {                 // Plan C
        Gb   = (u16*)alloc((size_t)MRF * 3072 * 2);
        A    = (u16*)d_out;
        QKVb = (u16*)d_out + 25165824;
    }
    u16* Obuf = Gb;

    zero_f32<<<96, 256, 0, stream>>>(M, 24576);
    calc_counts<<<1, 64, 0, stream>>>(sid, cnts);
    embed_k<<<32768, 192, 0, stream>>>(input_ids, tok_emb, pos_emb, turn_emb, Xb);

    if (allW) {
        transp_conv<<<dim3(72, 24, 4), dim3(32, 8), 0, stream>>>(mha_in_w,  WqkvT, 768, 2304);
        transp_conv<<<dim3(24, 24, 4), dim3(32, 8), 0, stream>>>(mha_out_w, WoT,   768, 768);
        transp_conv<<<dim3(96, 24, 4), dim3(32, 8), 0, stream>>>(ffn_w1,    W1T,   768, 3072);
        transp_conv<<<dim3(24, 96, 4), dim3(32, 8), 0, stream>>>(ffn_w2,    W2T,  3072, 768);
        transp_conv<<<dim3(24, 72, 4), dim3(32, 8), 0, stream>>>(gate_w,    WgT,  2304, 768);
        transp_conv<<<dim3(72, 24, 4), dim3(32, 8), 0, stream>>>(ca_in_w,   WcaT,  768, 2304);
        transp_conv<<<dim3(24, 24, 4), dim3(32, 8), 0, stream>>>(ca_out_w,  WcoT,  768, 768);
    }

    for (int l = 0; l < 4; ++l) {
        if (!allW) {
            transp_conv<<<dim3(72, 24), dim3(32, 8), 0, stream>>>(mha_in_w  + (size_t)l * 768 * 2304, WqkvT, 768, 2304);
            transp_conv<<<dim3(24, 24), dim3(32, 8), 0, stream>>>(mha_out_w + (size_t)l * 768 * 768,  WoT,   768, 768);
            transp_conv<<<dim3(96, 24), dim3(32, 8), 0, stream>>>(ffn_w1    + (size_t)l * 768 * 3072, W1T,   768, 3072);
            transp_conv<<<dim3(24, 96), dim3(32, 8), 0, stream>>>(ffn_w2    + (size_t)l * 3072 * 768, W2T,  3072, 768);
            transp_conv<<<dim3(24, 72), dim3(32, 8), 0, stream>>>(gate_w    + (size_t)l * 2304 * 768, WgT,  2304, 768);
            transp_conv<<<dim3(72, 24), dim3(32, 8), 0, stream>>>(ca_in_w   + (size_t)l * 768 * 2304, WcaT,  768, 2304);
            transp_conv<<<dim3(24, 24), dim3(32, 8), 0, stream>>>(ca_out_w  + (size_t)l * 768 * 768,  WcoT,  768, 768);
        }
        const u16* Wqkv_l = WqkvT + (size_t)(allW ? l : 0) * 2304 * 768;
        const u16* Wo_l   = WoT   + (size_t)(allW ? l : 0) * 768 * 768;
        const u16* W1_l   = W1T   + (size_t)(allW ? l : 0) * 768 * 3072;
        const u16* W2_l   = W2T   + (size_t)(allW ? l : 0) * 3072 * 768;
        const u16* Wg_l   = WgT   + (size_t)(allW ? l : 0) * 2304 * 768;
        const u16* Wca_l  = WcaT  + (size_t)(allW ? l : 0) * 768 * 2304;
        const u16* Wco_l  = WcoT  + (size_t)(allW ? l : 0) * 768 * 768;

        gather_mt<<<512, 256, 0, stream>>>(M, sid, mt);
        prep_ain<<<32768, 192, 0, stream>>>(Xb, mt, attn_mask, A);

        for (int c = 0; c < NCA; ++c) {
            u16* Ac = A + (size_t)c * MRA * 768;
            gemm_bt<0><<<dim3(18, MRA / 128), 256, 0, stream>>>(Ac, Wqkv_l, mha_in_b + l * 2304, QKVb, MRA, 2304, 768);
            attn_self<<<(MRA / 64) * 12, 256, 0, stream>>>(QKVb, Obuf);
            gemm_bt<0><<<dim3(6, MRA / 128), 256, 0, stream>>>(Obuf, Wo_l, mha_out_b + l * 768, Ac, MRA, 768, 768);
        }
        ln_res<<<32768, 256, 0, stream>>>(A, Xb, ln1_g + l * 768, ln1_b + l * 768, Hb);

        for (int c = 0; c < NCF; ++c) {
            u16* Hc = Hb + (size_t)c * MRF * 768;
            u16* Ac = A  + (size_t)c * MRF * 768;
            gemm_bt<1><<<dim3(24, MRF / 128), 256, 0, stream>>>(Hc, W1_l, ffn_b1 + l * 3072, Gb, MRF, 3072, 768);
            gemm_bt<0><<<dim3(6, MRF / 128), 256, 0, stream>>>(Gb, W2_l, ffn_b2 + l * 768, Ac, MRF, 768, 3072);
        }
        ln_res<<<32768, 256, 0, stream>>>(A, Hb, ln2_g + l * 768, ln2_b + l * 768, Xb);

        tc_mean<<<512, 256, 0, stream>>>(Xb, tcb);
        conv_bf16<<<96, 256, 0, stream>>>(M, Mb, 24576);
        gemm_bt<0><<<dim3(6, 4), 256, 0, stream>>>(tcb, Wca_l, ca_in_b + l * 2304, qc, 512, 768, 768);
        gemm_bt<0><<<dim3(12, 1), 256, 0, stream>>>(Mb, Wca_l + 768 * 768, ca_in_b + l * 2304 + 768, kvc, 32, 1536, 768);
        cross_attn<<<512, 256, 0, stream>>>(qc, kvc, cca);
        gemm_bt<0><<<dim3(6, 4), 256, 0, stream>>>(cca, Wco_l, ca_out_b + l * 768, ccp, 512, 768, 768);
        concat_fused<<<512, 256, 0, stream>>>(tcb, mt, ccp, Fu);
        gemm_bt<2><<<dim3(6, 4), 256, 0, stream>>>(Fu, Wg_l, gate_b + l * 768, gout, 512, 768, 2304);
        ln_upd<<<512, 256, 0, stream>>>(gout, mt, sn_g + l * 768, sn_b + l * 768, upd);
        scatter_mem<<<32, 256, 0, stream>>>(upd, sid, cnts, M);
    }

    final_out<<<98400, 256, 0, stream>>>(Xb, M, (float*)d_out);
}